// Round 6
// baseline (810.518 us; speedup 1.0000x reference)
//
#include <hip/hip_runtime.h>
#include <cmath>

#define BDIM 32
#define TDIM 577
#define TPAD 640
#define EDIM 1024
#define HDIM 16
#define DDIM 64
#define MDIM (BDIM * TDIM)     // 18464
#define MTILES 145
#define MPAD (MTILES * 128)    // 18560

typedef unsigned short u16;
typedef __bf16 bf16x8 __attribute__((ext_vector_type(8)));
typedef float f32x4 __attribute__((ext_vector_type(4)));
typedef u16 u16x8 __attribute__((ext_vector_type(8)));

// fp32 -> bf16 round-to-nearest-even (matches numpy/jax)
__device__ __forceinline__ u16 f2bf(float f) {
    unsigned int u = __float_as_uint(f);
    u = (u + 0x7FFFu + ((u >> 16) & 1u)) >> 16;
    return (u16)u;
}

// async global->LDS, 16B per lane. LDS dest is wave-uniform base; HW adds lane*16.
__device__ __forceinline__ void gload_lds16(const void* g, void* l) {
    __builtin_amdgcn_global_load_lds(
        (const __attribute__((address_space(1))) unsigned int*)g,
        (__attribute__((address_space(3))) unsigned int*)l, 16, 0, 0);
}

// ---------------------------------------------------------------------------
// cast x (fp32 [M,E]) -> bf16
// ---------------------------------------------------------------------------
__global__ __launch_bounds__(256) void cast_x(const float* __restrict__ x,
                                              u16* __restrict__ o, int nelem)
{
    int i = (blockIdx.x * 256 + threadIdx.x) * 8;
    if (i >= nelem) return;
    float4 a = *(const float4*)(x + i);
    float4 b = *(const float4*)(x + i + 4);
    u16x8 r;
    r[0] = f2bf(a.x); r[1] = f2bf(a.y); r[2] = f2bf(a.z); r[3] = f2bf(a.w);
    r[4] = f2bf(b.x); r[5] = f2bf(b.y); r[6] = f2bf(b.z); r[7] = f2bf(b.w);
    *(u16x8*)(o + i) = r;
}

// ---------------------------------------------------------------------------
// cast + transpose weights: W fp32 [K,N] -> Wt bf16 [N,K]
// ---------------------------------------------------------------------------
__global__ __launch_bounds__(256) void cast_wt(
    const float* __restrict__ W0, const float* __restrict__ W1,
    const float* __restrict__ W2, const float* __restrict__ W3,
    u16* __restrict__ T0, u16* __restrict__ T1,
    u16* __restrict__ T2, u16* __restrict__ T3)
{
    __shared__ float tile[32][33];
    const int z = blockIdx.z;
    const float* __restrict__ W = (z == 0) ? W0 : (z == 1) ? W1 : (z == 2) ? W2 : W3;
    u16* __restrict__ T = (z == 0) ? T0 : (z == 1) ? T1 : (z == 2) ? T2 : T3;
    const int bn = blockIdx.x * 32;
    const int bk = blockIdx.y * 32;
    const int tx = threadIdx.x & 31, ty = threadIdx.x >> 5;
#pragma unroll
    for (int p = 0; p < 4; ++p) {
        int k = bk + p * 8 + ty;
        tile[p * 8 + ty][tx] = W[(size_t)k * EDIM + bn + tx];
    }
    __syncthreads();
#pragma unroll
    for (int p = 0; p < 4; ++p) {
        int n = bn + p * 8 + ty;
        T[(size_t)n * EDIM + bk + tx] = f2bf(tile[tx][p * 8 + ty]);
    }
}

// ---------------------------------------------------------------------------
// Fused QKV bf16 MFMA GEMM. One block owns a 128x128 (m,n) tile and loops
// z = q,k,v INSIDE: the A-panel staging for z=1,2 re-reads addresses just
// fetched at z=0 -> guaranteed L2 hits, shortening the vmcnt(0) barrier
// drains that bound round-5 (MfmaUtil 22%, nothing saturated). W panels are
// L2-resident per XCD (grid.x=8 -> XCD = n-tile; 3 x 256 KB < 4 MB).
// BK=64, two 32-k panels [p][128][32]; 32 MFMA/wave per drain.
// Epilogue: z0/z1 -> [B,H,TPAD,D]; z2 -> V^T [B,H,D,TPAD]. Q pre-scaled by
// 0.125 (exact power-of-2 in bf16; folds softmax 1/sqrt(D) into the GEMM).
// ---------------------------------------------------------------------------
__global__ __launch_bounds__(256, 4) void gemm_qkv(
    const u16* __restrict__ A, const u16* __restrict__ Wt,  // Wt: [3][N][K]
    const float* __restrict__ bq, const float* __restrict__ bk,
    const float* __restrict__ bv,
    u16* __restrict__ qo, u16* __restrict__ ko, u16* __restrict__ vto)
{
    __shared__ u16 As[128 * 64];   // 2 panels x [128][32], 16 KB
    __shared__ u16 Bs[128 * 64];

    const int tid = threadIdx.x;
    const int wave = tid >> 6;
    const int lane = tid & 63;
    const int mlane = lane & 15;
    const int quad = lane >> 4;
    const int wm = wave >> 1;
    const int wn = wave & 1;
    const int m0 = blockIdx.y * 128;
    const int n0 = blockIdx.x * 128;

    for (int z = 0; z < 3; ++z) {
        const u16* __restrict__ W = Wt + (size_t)z * EDIM * EDIM;
        const float* __restrict__ bias = (z == 0) ? bq : ((z == 1) ? bk : bv);
        u16* __restrict__ dst = (z == 0) ? qo : ((z == 1) ? ko : vto);

        f32x4 acc[4][4];
#pragma unroll
        for (int i = 0; i < 4; ++i)
#pragma unroll
            for (int j = 0; j < 4; ++j) acc[i][j] = (f32x4)(0.f);

        for (int k0 = 0; k0 < EDIM; k0 += 64) {
#pragma unroll
            for (int r = 0; r < 4; ++r) {
                int c = r * 256 + tid;
                int p = c >> 9, row = (c >> 2) & 127, j4 = c & 3;
                int koff = k0 + p * 32 + j4 * 8;
                gload_lds16(A + (size_t)(m0 + row) * EDIM + koff,
                            &As[(r * 256 + wave * 64) * 8]);
                gload_lds16(W + (size_t)(n0 + row) * EDIM + koff,
                            &Bs[(r * 256 + wave * 64) * 8]);
            }
            __syncthreads();

#pragma unroll
            for (int ks = 0; ks < 2; ++ks) {
                bf16x8 af[4], bfr[4];
#pragma unroll
                for (int t = 0; t < 4; ++t) {
                    af[t]  = *(const bf16x8*)&As[ks * 4096 + (wm * 64 + t * 16 + mlane) * 32 + quad * 8];
                    bfr[t] = *(const bf16x8*)&Bs[ks * 4096 + (wn * 64 + t * 16 + mlane) * 32 + quad * 8];
                }
#pragma unroll
                for (int i = 0; i < 4; ++i)
#pragma unroll
                    for (int j = 0; j < 4; ++j)
                        acc[i][j] = __builtin_amdgcn_mfma_f32_16x16x32_bf16(af[i], bfr[j], acc[i][j], 0, 0, 0);
            }
            __syncthreads();
        }

        // epilogue: C/D layout col = lane&15, row = quad*4 + reg
#pragma unroll
        for (int j = 0; j < 4; ++j) {
            int n = n0 + wn * 64 + j * 16 + mlane;
            float bvv = bias[n];
            int h = n >> 6, d = n & 63;
#pragma unroll
            for (int i = 0; i < 4; ++i) {
                int mb = m0 + wm * 64 + i * 16 + quad * 4;
#pragma unroll
                for (int r = 0; r < 4; ++r) {
                    int gm = mb + r;
                    if (gm < MDIM) {
                        int b = gm / TDIM, t = gm - b * TDIM;
                        float val = acc[i][j][r] + bvv;
                        if (z == 0) val *= 0.125f;     // fold 1/sqrt(D); exact
                        u16 vb16 = f2bf(val);
                        if (z == 2)
                            dst[((size_t)(b * HDIM + h) * DDIM + d) * TPAD + t] = vb16;
                        else
                            dst[((size_t)(b * HDIM + h) * TPAD + t) * DDIM + d] = vb16;
                    }
                }
            }
        }
    }
}

// ---------------------------------------------------------------------------
// Output-projection GEMM (round-5 structure, mode-1 only): fp32 [M,N] out.
// ---------------------------------------------------------------------------
__global__ __launch_bounds__(256, 4) void gemm_out(
    const u16* __restrict__ A, const u16* __restrict__ Wt,
    const float* __restrict__ bias, float* __restrict__ dst)
{
    __shared__ u16 As[128 * 64];
    __shared__ u16 Bs[128 * 64];

    const int tid = threadIdx.x;
    const int wave = tid >> 6;
    const int lane = tid & 63;
    const int mlane = lane & 15;
    const int quad = lane >> 4;
    const int wm = wave >> 1;
    const int wn = wave & 1;
    const int m0 = blockIdx.y * 128;
    const int n0 = blockIdx.x * 128;

    f32x4 acc[4][4];
#pragma unroll
    for (int i = 0; i < 4; ++i)
#pragma unroll
        for (int j = 0; j < 4; ++j) acc[i][j] = (f32x4)(0.f);

    for (int k0 = 0; k0 < EDIM; k0 += 64) {
#pragma unroll
        for (int r = 0; r < 4; ++r) {
            int c = r * 256 + tid;
            int p = c >> 9, row = (c >> 2) & 127, j4 = c & 3;
            int koff = k0 + p * 32 + j4 * 8;
            gload_lds16(A + (size_t)(m0 + row) * EDIM + koff,
                        &As[(r * 256 + wave * 64) * 8]);
            gload_lds16(Wt + (size_t)(n0 + row) * EDIM + koff,
                        &Bs[(r * 256 + wave * 64) * 8]);
        }
        __syncthreads();

#pragma unroll
        for (int ks = 0; ks < 2; ++ks) {
            bf16x8 af[4], bfr[4];
#pragma unroll
            for (int t = 0; t < 4; ++t) {
                af[t]  = *(const bf16x8*)&As[ks * 4096 + (wm * 64 + t * 16 + mlane) * 32 + quad * 8];
                bfr[t] = *(const bf16x8*)&Bs[ks * 4096 + (wn * 64 + t * 16 + mlane) * 32 + quad * 8];
            }
#pragma unroll
            for (int i = 0; i < 4; ++i)
#pragma unroll
                for (int j = 0; j < 4; ++j)
                    acc[i][j] = __builtin_amdgcn_mfma_f32_16x16x32_bf16(af[i], bfr[j], acc[i][j], 0, 0, 0);
        }
        __syncthreads();
    }

#pragma unroll
    for (int j = 0; j < 4; ++j) {
        int n = n0 + wn * 64 + j * 16 + mlane;
        float bvv = bias[n];
#pragma unroll
        for (int i = 0; i < 4; ++i) {
            int mb = m0 + wm * 64 + i * 16 + quad * 4;
#pragma unroll
            for (int r = 0; r < 4; ++r) {
                int gm = mb + r;
                if (gm < MDIM) dst[(size_t)gm * EDIM + n] = acc[i][j][r] + bvv;
            }
        }
    }
}

// ---------------------------------------------------------------------------
// bf16 MFMA flash attention. Q arrives pre-scaled by 1/sqrt(D) (folded into
// the QKV GEMM epilogue). Mask path hoisted: chunks 0..8 are fully valid
// (575 < 577), only the last chunk branches into the cndmask path.
// ---------------------------------------------------------------------------
__global__ __launch_bounds__(256) void attn_mfma(
    const u16* __restrict__ qg, const u16* __restrict__ kg,
    const u16* __restrict__ vtg, u16* __restrict__ outg)
{
    __shared__ u16 Qs[4096];    // [kc][t64][32]
    __shared__ u16 Ks[4096];    // [kc][n64][32]
    __shared__ u16 Vts[4096];   // [kc][d64][32]
    __shared__ u16 Ps[4608];    // 4 waves * 2 panels * 16 rows * 36 (padded)

    const int tid = threadIdx.x;
    const int wave = tid >> 6;
    const int lane = tid & 63;
    const int ml = lane & 15;
    const int quad = lane >> 4;
    const int h = blockIdx.y, b = blockIdx.z;
    const int q0 = blockIdx.x * 64;
    const u16* qb = qg + ((size_t)b * HDIM + h) * TPAD * DDIM;
    const u16* kb = kg + ((size_t)b * HDIM + h) * TPAD * DDIM;
    const u16* vb = vtg + ((size_t)b * HDIM + h) * DDIM * TPAD;

#pragma unroll
    for (int r = 0; r < 2; ++r) {
        int c = r * 256 + tid;
        int row = (c >> 2) & 63, kc = c >> 8, d8 = c & 3;
        gload_lds16(qb + (size_t)(q0 + row) * DDIM + kc * 32 + d8 * 8,
                    &Qs[(r * 256 + wave * 64) * 8]);
    }
    __syncthreads();

    bf16x8 aq0 = *(const bf16x8*)&Qs[(wave * 16 + ml) * 32 + quad * 8];
    bf16x8 aq1 = *(const bf16x8*)&Qs[2048 + (wave * 16 + ml) * 32 + quad * 8];

    f32x4 oacc[4];
#pragma unroll
    for (int dt = 0; dt < 4; ++dt) oacc[dt] = (f32x4)(0.f);
    float m_i[4], l_i[4];
#pragma unroll
    for (int r = 0; r < 4; ++r) { m_i[r] = -INFINITY; l_i[r] = 0.f; }

    for (int kv0 = 0; kv0 < TDIM; kv0 += 64) {
        __syncthreads();
#pragma unroll
        for (int r = 0; r < 2; ++r) {
            int c = r * 256 + tid;
            int row = (c >> 2) & 63, kc = c >> 8, d8 = c & 3;
            gload_lds16(kb + (size_t)(kv0 + row) * DDIM + kc * 32 + d8 * 8,
                        &Ks[(r * 256 + wave * 64) * 8]);
            gload_lds16(vb + (size_t)row * TPAD + kv0 + kc * 32 + d8 * 8,
                        &Vts[(r * 256 + wave * 64) * 8]);
        }
        __syncthreads();

        f32x4 sacc[4];
#pragma unroll
        for (int jt = 0; jt < 4; ++jt) {
            bf16x8 bk0 = *(const bf16x8*)&Ks[(jt * 16 + ml) * 32 + quad * 8];
            bf16x8 bk1 = *(const bf16x8*)&Ks[2048 + (jt * 16 + ml) * 32 + quad * 8];
            f32x4 sa = (f32x4)(0.f);
            sa = __builtin_amdgcn_mfma_f32_16x16x32_bf16(aq0, bk0, sa, 0, 0, 0);
            sa = __builtin_amdgcn_mfma_f32_16x16x32_bf16(aq1, bk1, sa, 0, 0, 0);
            sacc[jt] = sa;
        }

        float p[4][4];
        const bool full = (kv0 + 64 <= TDIM);   // wave-uniform
#pragma unroll
        for (int r = 0; r < 4; ++r) {
            float cm;
            if (full) {
#pragma unroll
                for (int jt = 0; jt < 4; ++jt) p[jt][r] = sacc[jt][r];
                cm = fmaxf(fmaxf(p[0][r], p[1][r]), fmaxf(p[2][r], p[3][r]));
            } else {
                cm = -INFINITY;
#pragma unroll
                for (int jt = 0; jt < 4; ++jt) {
                    bool valid = (kv0 + jt * 16 + ml) < TDIM;
                    float sv = valid ? sacc[jt][r] : -INFINITY;
                    p[jt][r] = sv;
                    cm = fmaxf(cm, sv);
                }
            }
            cm = fmaxf(cm, __shfl_xor(cm, 1, 64));
            cm = fmaxf(cm, __shfl_xor(cm, 2, 64));
            cm = fmaxf(cm, __shfl_xor(cm, 4, 64));
            cm = fmaxf(cm, __shfl_xor(cm, 8, 64));
            float mn = fmaxf(m_i[r], cm);
            float alpha = __expf(m_i[r] - mn);
            float rs = 0.f;
#pragma unroll
            for (int jt = 0; jt < 4; ++jt) {
                float e = __expf(p[jt][r] - mn);
                p[jt][r] = e;
                rs += e;
            }
            rs += __shfl_xor(rs, 1, 64);
            rs += __shfl_xor(rs, 2, 64);
            rs += __shfl_xor(rs, 4, 64);
            rs += __shfl_xor(rs, 8, 64);
            l_i[r] = l_i[r] * alpha + rs;
            m_i[r] = mn;
#pragma unroll
            for (int dt = 0; dt < 4; ++dt) oacc[dt][r] *= alpha;
        }

#pragma unroll
        for (int jt = 0; jt < 4; ++jt)
#pragma unroll
            for (int r = 0; r < 4; ++r)
                Ps[wave * 1152 + (jt >> 1) * 576 + (quad * 4 + r) * 36 + (jt & 1) * 16 + ml]
                    = f2bf(p[jt][r]);
        __syncthreads();

        bf16x8 pf0 = *(const bf16x8*)&Ps[wave * 1152 + ml * 36 + quad * 8];
        bf16x8 pf1 = *(const bf16x8*)&Ps[wave * 1152 + 576 + ml * 36 + quad * 8];

#pragma unroll
        for (int dt = 0; dt < 4; ++dt) {
            bf16x8 bv0 = *(const bf16x8*)&Vts[(dt * 16 + ml) * 32 + quad * 8];
            bf16x8 bv1 = *(const bf16x8*)&Vts[2048 + (dt * 16 + ml) * 32 + quad * 8];
            oacc[dt] = __builtin_amdgcn_mfma_f32_16x16x32_bf16(pf0, bv0, oacc[dt], 0, 0, 0);
            oacc[dt] = __builtin_amdgcn_mfma_f32_16x16x32_bf16(pf1, bv1, oacc[dt], 0, 0, 0);
        }
    }

#pragma unroll
    for (int r = 0; r < 4; ++r) {
        int t = q0 + wave * 16 + quad * 4 + r;
        if (t >= TDIM) continue;
        float inv = 1.f / l_i[r];
        size_t rowoff = ((size_t)b * TDIM + t) * EDIM + h * DDIM;
#pragma unroll
        for (int dt = 0; dt < 4; ++dt)
            outg[rowoff + dt * 16 + ml] = f2bf(oacc[dt][r] * inv);
    }
}

// ---------------------------------------------------------------------------
extern "C" void kernel_launch(void* const* d_in, const int* in_sizes, int n_in,
                              void* d_out, int out_size, void* d_ws, size_t ws_size,
                              hipStream_t stream)
{
    const float* x  = (const float*)d_in[0];
    const float* Wq = (const float*)d_in[1];
    const float* bq = (const float*)d_in[2];
    const float* Wk = (const float*)d_in[3];
    const float* bk = (const float*)d_in[4];
    const float* Wv = (const float*)d_in[5];
    const float* bv = (const float*)d_in[6];
    const float* Wo = (const float*)d_in[7];
    const float* bo = (const float*)d_in[8];
    float* out = (float*)d_out;

    const size_t hsz = (size_t)BDIM * HDIM * TPAD * DDIM;  // 20,971,520 elems
    u16* qb  = (u16*)d_ws;                     // bf16 [B,H,TPAD,D]  (pre-scaled)
    u16* kb  = qb + hsz;                       // bf16 [B,H,TPAD,D]
    u16* vtb = kb + hsz;                       // bf16 [B,H,D,TPAD]
    u16* xb  = vtb + hsz;                      // bf16 x [MPAD][E]
    u16* abb = xb;                             // attn out aliases xb (xb dead by then)
    u16* wtq = xb + (size_t)MPAD * EDIM;       // bf16 W^T [3][N][K] contiguous
    u16* wtk = wtq + (size_t)EDIM * EDIM;
    u16* wtv = wtk + (size_t)EDIM * EDIM;
    u16* wto = wtv + (size_t)EDIM * EDIM;
    // ws: 125.8 MB + 38.0 MB + 8.4 MB = 172.2 MB

    cast_x<<<(MDIM * EDIM / 8 + 255) / 256, 256, 0, stream>>>(x, xb, MDIM * EDIM);
    cast_wt<<<dim3(32, 32, 4), 256, 0, stream>>>(Wq, Wk, Wv, Wo, wtq, wtk, wtv, wto);

    gemm_qkv<<<dim3(EDIM / 128, MTILES), 256, 0, stream>>>(
        xb, wtq, bq, bk, bv, qb, kb, vtb);

    attn_mfma<<<dim3(TPAD / 64, HDIM, BDIM), 256, 0, stream>>>(qb, kb, vtb, abb);

    gemm_out<<<dim3(EDIM / 128, MTILES), 256, 0, stream>>>(abb, wto, bo, out);
}